// Round 2
// baseline (328.631 us; speedup 1.0000x reference)
//
#include <hip/hip_runtime.h>
#include <math.h>

// Problem constants
#define NB   128   // batch
#define NC   128   // channels
#define NN   170   // nodes
#define NT   12    // length
#define MP   176   // padded embedding dim (170 -> 176, zero-filled tail)

// ---------------------------------------------------------------------------
// K1: xs[b][c][n] = sum_t x[b][c][n][t]
// Layout: x is [B][C][N][T] contiguous; each thread owns one (b,c,n), reads
// 12 consecutive floats (3x float4, 48B aligned), writes one float (coalesced).
// Grid is exactly B*C*N/256 = 10880 blocks.
// ---------------------------------------------------------------------------
__global__ __launch_bounds__(256) void k1_reduce_t(const float* __restrict__ x,
                                                   float* __restrict__ xs) {
    int idx = blockIdx.x * 256 + threadIdx.x;          // [0, 2785280)
    const float4* xp = reinterpret_cast<const float4*>(x) + (size_t)idx * 3;
    float4 a = xp[0], b = xp[1], c = xp[2];
    xs[idx] = (a.x + a.y + a.z + a.w) + (b.x + b.y + b.z + b.w)
            + (c.x + c.y + c.z + c.w);
}

// ---------------------------------------------------------------------------
// K2: E_d[b][n][m] = tanh( sum_c xs[b][c][n] * E_s[c][m] ),  m in [0,176)
// (m in [170,176) gets tanh(0)=0 -> zero padding for K3's dot over m).
// Tiled fp32 GEMM: 64(n) x 64(m) block tile, K-chunks of 16 over c,
// 256 threads as 16x16, 4x4 register tile per thread.
// Grid: x = nt + 3*mt (nt,mt in [0,3)), y = batch.
// ---------------------------------------------------------------------------
__global__ __launch_bounds__(256) void k2_embed(const float* __restrict__ xs,
                                                const float* __restrict__ Es,
                                                float* __restrict__ Ed) {
    const int b  = blockIdx.y;
    const int nt = blockIdx.x % 3;
    const int mt = blockIdx.x / 3;
    const int n0 = nt * 64, m0 = mt * 64;
    const int t  = threadIdx.x;
    const int tx = t % 16, ty = t / 16;

    __shared__ __align__(16) float As[16][68];   // [c-chunk][n-tile], +4 pad
    __shared__ __align__(16) float Bs[16][68];   // [c-chunk][m-tile], +4 pad

    float acc[4][4] = {};

    for (int c0 = 0; c0 < NC; c0 += 16) {
        #pragma unroll
        for (int it = 0; it < 4; ++it) {
            int e  = t + it * 256;               // [0,1024)
            int kc = e / 64, i = e % 64;
            int n = n0 + i;
            As[kc][i] = (n < NN) ? xs[((b * NC) + (c0 + kc)) * NN + n] : 0.f;
            int m = m0 + i;
            Bs[kc][i] = (m < NN) ? Es[(c0 + kc) * NN + m] : 0.f;
        }
        __syncthreads();
        #pragma unroll
        for (int kc = 0; kc < 16; ++kc) {
            float4 av4 = *reinterpret_cast<const float4*>(&As[kc][ty * 4]);
            float4 bv4 = *reinterpret_cast<const float4*>(&Bs[kc][tx * 4]);
            float av[4] = {av4.x, av4.y, av4.z, av4.w};
            float bv[4] = {bv4.x, bv4.y, bv4.z, bv4.w};
            #pragma unroll
            for (int ii = 0; ii < 4; ++ii)
                #pragma unroll
                for (int jj = 0; jj < 4; ++jj)
                    acc[ii][jj] = fmaf(av[ii], bv[jj], acc[ii][jj]);
        }
        __syncthreads();
    }

    #pragma unroll
    for (int ii = 0; ii < 4; ++ii) {
        int n = n0 + ty * 4 + ii;
        if (n >= NN) continue;
        #pragma unroll
        for (int jj = 0; jj < 4; ++jj) {
            int m = m0 + tx * 4 + jj;
            if (m < MP) Ed[((size_t)(b * NN + n)) * MP + m] = tanhf(acc[ii][jj]);
        }
    }
}

// ---------------------------------------------------------------------------
// K3: per (b, 64-row tile): scores[n][k] = relu( (E_d[b,n,:].E_d[b,k,:]) /
// sqrt(C) ), then row softmax over k in [0,170), write P[b][n][k].
// k processed in 3 tiles of 64 into a persistent LDS scores buffer; each
// k-tile is a 64x64 fp32 GEMM over m (11 chunks of 16), 4x4 register tiles.
// Softmax: one wave per row (4 waves x 16 rows).
// ---------------------------------------------------------------------------
__global__ __launch_bounds__(256) void k3_scores(const float* __restrict__ Ed,
                                                 float* __restrict__ P) {
    const int b  = blockIdx.y;
    const int n0 = blockIdx.x * 64;
    const int t  = threadIdx.x;
    const int tx = t % 16, ty = t / 16;

    __shared__ __align__(16) float As[16][68];    // [m-chunk][row-tile]
    __shared__ __align__(16) float Bs[16][68];    // [m-chunk][k-tile]
    __shared__ __align__(16) float Sc[64][176];   // scores row tile

    const float* __restrict__ Edb = Ed + (size_t)b * NN * MP;
    const float scale = 0.08838834764831845f;     // 1/sqrt(128)

    for (int kt = 0; kt < 3; ++kt) {
        const int k0 = kt * 64;
        float acc[4][4] = {};
        for (int mc = 0; mc < MP; mc += 16) {
            __syncthreads();                       // As/Bs reuse barrier
            #pragma unroll
            for (int it = 0; it < 4; ++it) {
                int e  = t + it * 256;             // [0,1024)
                int i  = e / 16, mm = e % 16;
                int n = n0 + i;
                As[mm][i] = (n < NN) ? Edb[(size_t)n * MP + mc + mm] : 0.f;
                int k = k0 + i;
                Bs[mm][i] = (k < NN) ? Edb[(size_t)k * MP + mc + mm] : 0.f;
            }
            __syncthreads();
            #pragma unroll
            for (int mm = 0; mm < 16; ++mm) {
                float4 av4 = *reinterpret_cast<const float4*>(&As[mm][ty * 4]);
                float4 bv4 = *reinterpret_cast<const float4*>(&Bs[mm][tx * 4]);
                float av[4] = {av4.x, av4.y, av4.z, av4.w};
                float bv[4] = {bv4.x, bv4.y, bv4.z, bv4.w};
                #pragma unroll
                for (int ii = 0; ii < 4; ++ii)
                    #pragma unroll
                    for (int jj = 0; jj < 4; ++jj)
                        acc[ii][jj] = fmaf(av[ii], bv[jj], acc[ii][jj]);
            }
        }
        // relu + scale, park this 64x64 chunk in the scores LDS buffer.
        // GUARD (R1 fix): in the kt=2 tile, cols k0+tx*4 reach 188..191 for
        // tx>=12, overflowing Sc's 176-col rows into the NEXT row's cols
        // 0..15 (zeroing real scores -> diag flips -> absmax 1.0). Those
        // k>=176 accumulators are zero-padding garbage anyway; skip them.
        // Stores are 4-aligned and MP%4==0, so (k0+tx*4 < MP) is exact.
        if (k0 + tx * 4 < MP) {
            #pragma unroll
            for (int ii = 0; ii < 4; ++ii) {
                float4 v;
                v.x = fmaxf(acc[ii][0] * scale, 0.f);
                v.y = fmaxf(acc[ii][1] * scale, 0.f);
                v.z = fmaxf(acc[ii][2] * scale, 0.f);
                v.w = fmaxf(acc[ii][3] * scale, 0.f);
                *reinterpret_cast<float4*>(&Sc[ty * 4 + ii][k0 + tx * 4]) = v;
            }
        }
    }
    __syncthreads();

    // Row softmax: wave w owns rows [w*16, w*16+16). Each lane covers
    // k = lane, lane+64, lane+128 (masked at 170). relu => values >= 0.
    const int wave = t / 64, lane = t % 64;
    for (int rr = 0; rr < 16; ++rr) {
        int r = wave * 16 + rr;
        int n = n0 + r;
        if (n >= NN) continue;                     // wave-uniform branch
        float v0 = Sc[r][lane];
        float v1 = Sc[r][lane + 64];
        int  k2i = lane + 128;
        bool has2 = (k2i < NN);
        float v2 = has2 ? Sc[r][k2i] : -1.f;       // values >= 0, so -1 is safe
        float m = fmaxf(fmaxf(v0, v1), v2);
        #pragma unroll
        for (int off = 32; off; off >>= 1) m = fmaxf(m, __shfl_xor(m, off, 64));
        float e0 = __expf(v0 - m);
        float e1 = __expf(v1 - m);
        float e2 = has2 ? __expf(v2 - m) : 0.f;
        float s = e0 + e1 + e2;
        #pragma unroll
        for (int off = 32; off; off >>= 1) s += __shfl_xor(s, off, 64);
        float inv = 1.f / s;
        float* Pr = P + (size_t)b * (NN * NN) + (size_t)n * NN;
        Pr[lane]      = e0 * inv;
        Pr[lane + 64] = e1 * inv;
        if (has2) Pr[k2i] = e2 * inv;
    }
}

// ---------------------------------------------------------------------------
// K4: out[n][k] = ( mean_b P[b][n][k] > 0.5 ) ? 1 : 0
// ---------------------------------------------------------------------------
__global__ __launch_bounds__(256) void k4_mean_thresh(const float* __restrict__ P,
                                                      float* __restrict__ out) {
    int e = blockIdx.x * 256 + threadIdx.x;
    if (e >= NN * NN) return;
    float s = 0.f;
    #pragma unroll 8
    for (int b = 0; b < NB; ++b) s += P[(size_t)b * (NN * NN) + e];
    out[e] = (s * (1.f / NB) > 0.5f) ? 1.f : 0.f;
}

// ---------------------------------------------------------------------------
// Workspace layout (floats):
//   [0, 3699200)          : P  (128*170*170)  -- also reused as xs (2785280)
//                            xs is dead once K2 finishes; K3 overwrites it.
//   [3699200, 7528960)    : E_d (128*170*176)
// Total = 30,115,840 bytes.
// ---------------------------------------------------------------------------
extern "C" void kernel_launch(void* const* d_in, const int* in_sizes, int n_in,
                              void* d_out, int out_size, void* d_ws, size_t ws_size,
                              hipStream_t stream) {
    const float* x  = (const float*)d_in[0];   // [128,128,170,12] f32
    const float* Es = (const float*)d_in[1];   // [128,170] f32
    float* out = (float*)d_out;                // [170,170] f32
    float* wsf = (float*)d_ws;

    float* P  = wsf;                 // 3,699,200 floats
    float* xs = wsf;                 // aliases P region; dead before K3 writes P
    float* Ed = wsf + 3699200;       // 3,829,760 floats

    k1_reduce_t<<<10880, 256, 0, stream>>>(x, xs);
    k2_embed<<<dim3(9, 128), 256, 0, stream>>>(xs, Es, Ed);
    k3_scores<<<dim3(3, 128), 256, 0, stream>>>(Ed, P);
    k4_mean_thresh<<<(NN * NN + 255) / 256, 256, 0, stream>>>(P, out);
}

// Round 3
// 250.710 us; speedup vs baseline: 1.3108x; 1.3108x over previous
//
#include <hip/hip_runtime.h>
#include <math.h>

// Problem constants
#define NB 128     // batch
#define NC 128     // channels
#define NN 170     // nodes
#define NT 12      // length
#define MP 176     // padded row stride (16B-aligned rows) for xs/Es/Ed/P
#define BSROW 196  // LDS row stride for staged tiles (196%32==4 -> bank spread)

// Workspace regions (floats)
#define XS_SZ  (NB * NC * MP)   // 2,883,584
#define ESP_SZ (NC * MP)        //    22,528
#define P_SZ   (NB * NN * MP)   // 3,829,760
#define ED_SZ  (NB * NN * MP)   // 3,829,760

// ---------------------------------------------------------------------------
// K1: xs[b][c][n] = sum_t x[b][c][n][t], written PADDED to stride 176 with
// zeros in cols [170,176). Fully-coalesced: each wave loads 192 consecutive
// float4 (3 loads/lane), then gathers the 3 partial sums of its group via
// __shfl (ds_bpermute) -- no LDS, no barriers, no strided loads.
// Blocks >= 10880 instead produce Es padded to stride 176 (Esp).
// ---------------------------------------------------------------------------
__global__ __launch_bounds__(256) void k1_reduce_pad(const float* __restrict__ x,
                                                     const float* __restrict__ Es,
                                                     float* __restrict__ xs,
                                                     float* __restrict__ Esp) {
    if (blockIdx.x >= 10880) {              // Es padding tail: 88 blocks
        int idx = (blockIdx.x - 10880) * 256 + threadIdx.x;
        if (idx < ESP_SZ) {
            int c = idx / MP, m = idx % MP;
            Esp[idx] = (m < NN) ? Es[c * NN + m] : 0.f;
        }
        return;
    }
    const int w    = blockIdx.x * 4 + (threadIdx.x >> 6);  // global wave id
    const int lane = threadIdx.x & 63;
    const float4* x4 = reinterpret_cast<const float4*>(x) + (size_t)w * 192;
    float4 f0 = x4[lane], f1 = x4[lane + 64], f2 = x4[lane + 128];
    float p0 = (f0.x + f0.y) + (f0.z + f0.w);
    float p1 = (f1.x + f1.y) + (f1.z + f1.w);
    float p2 = (f2.x + f2.y) + (f2.z + f2.w);
    // group 'lane' needs partial sums of slots 3*lane+{0,1,2}; slot s lives in
    // reg (s>>6) of lane (s&63).
    float tot = 0.f;
    #pragma unroll
    for (int j = 0; j < 3; ++j) {
        int s = 3 * lane + j;
        int src = s & 63, reg = s >> 6;
        float a0 = __shfl(p0, src, 64);
        float a1 = __shfl(p1, src, 64);
        float a2 = __shfl(p2, src, 64);
        tot += (reg == 0) ? a0 : (reg == 1) ? a1 : a2;
    }
    int g  = w * 64 + lane;                 // global group in [0, 2785280)
    int bc = g / NN, n = g - bc * NN;
    xs[(size_t)bc * MP + n] = tot;
    if (n < MP - NN) xs[(size_t)bc * MP + NN + n] = 0.f;   // zero the pad cols
}

// ---------------------------------------------------------------------------
// K2: Ed[b][n][m] = tanh( sum_c xs[b][c][n] * Esp[c][m] ), m in [0,176).
// Block = (b, 32-row tile). 256 threads as 16tx x 16ty; thread owns rows
// ty*2+{0,1}, cols tx*4 + {0,64,128} (192 cols computed, cols>=176 dropped).
// K-loop: 8 chunks of 16 channels; A(16x32) + B(16x192) staged per chunk.
// Pad cols [170,176) of Ed get tanh(0)=0 automatically (Esp pad is zero).
// ---------------------------------------------------------------------------
__global__ __launch_bounds__(256) void k2_embed(const float* __restrict__ xs,
                                                const float* __restrict__ Esp,
                                                float* __restrict__ Ed) {
    const int b = blockIdx.y, n0 = blockIdx.x * 32;
    const int t = threadIdx.x, tx = t & 15, ty = t >> 4;
    __shared__ __align__(16) float As[16][36];      // [c][n], 2.3 KB
    __shared__ __align__(16) float Bs[16][BSROW];   // [c][m], 12.5 KB

    float acc[2][12] = {};
    for (int c0 = 0; c0 < NC; c0 += 16) {
        __syncthreads();
        if (t < 128) {                               // A: 128 float4
            int c = t >> 3, q = t & 7;
            float4 v = *reinterpret_cast<const float4*>(
                xs + ((size_t)(b * NC + c0 + c)) * MP + n0 + q * 4);
            *reinterpret_cast<float4*>(&As[c][q * 4]) = v;
        }
        #pragma unroll
        for (int it = 0; it < 3; ++it) {             // B: 768 float4
            int idx = t + it * 256;                  // [0,768)
            int c = idx / 48, mq = idx - c * 48;     // mq in [0,48)
            float4 v = make_float4(0.f, 0.f, 0.f, 0.f);
            if (mq < 44)
                v = *reinterpret_cast<const float4*>(Esp + (c0 + c) * MP + mq * 4);
            *reinterpret_cast<float4*>(&Bs[c][mq * 4]) = v;
        }
        __syncthreads();
        #pragma unroll
        for (int cc = 0; cc < 16; ++cc) {
            float2 av = *reinterpret_cast<const float2*>(&As[cc][ty * 2]);
            float a[2] = {av.x, av.y};
            float bb[12];
            #pragma unroll
            for (int off = 0; off < 3; ++off) {
                float4 bv = *reinterpret_cast<const float4*>(&Bs[cc][tx * 4 + off * 64]);
                bb[off * 4 + 0] = bv.x; bb[off * 4 + 1] = bv.y;
                bb[off * 4 + 2] = bv.z; bb[off * 4 + 3] = bv.w;
            }
            #pragma unroll
            for (int ii = 0; ii < 2; ++ii)
                #pragma unroll
                for (int jj = 0; jj < 12; ++jj)
                    acc[ii][jj] = fmaf(a[ii], bb[jj], acc[ii][jj]);
        }
    }
    #pragma unroll
    for (int ii = 0; ii < 2; ++ii) {
        int n = n0 + ty * 2 + ii;
        if (n >= NN) continue;
        float* Erow = Ed + ((size_t)(b * NN + n)) * MP;
        #pragma unroll
        for (int off = 0; off < 3; ++off) {
            int m = tx * 4 + off * 64;
            if (m >= MP) continue;                   // off==2 && tx>=12
            float4 v;
            v.x = tanhf(acc[ii][off * 4 + 0]);
            v.y = tanhf(acc[ii][off * 4 + 1]);
            v.z = tanhf(acc[ii][off * 4 + 2]);
            v.w = tanhf(acc[ii][off * 4 + 3]);
            *reinterpret_cast<float4*>(Erow + m) = v;
        }
    }
}

// ---------------------------------------------------------------------------
// K3: scores[n][k] = relu( dot_m(Ed[b,n,:], Ed[b,k,:]) / sqrt(C) ), row
// softmax over k<170, P[b][n][k] (P padded to stride 176).
// Block = (b, 32-row tile); same 16x16/acc[2][12] shape as K2. Single LDS
// buffer Bs[mm][k] = Ed[b][k][mc+mm] for ALL k in [0,192) (zeros past 170),
// so the A-fragment is just Bs[mm][r0+ty*2] -- no separate A staging.
// Softmax is fully in-register: shfl_xor reduction across the 16-lane
// tx-group (offsets 1,2,4,8). 22 barriers/block, grid 768 blocks.
// ---------------------------------------------------------------------------
__global__ __launch_bounds__(256) void k3_scores(const float* __restrict__ Ed,
                                                 float* __restrict__ P) {
    const int b = blockIdx.y, r0 = blockIdx.x * 32;
    const int t = threadIdx.x, tx = t & 15, ty = t >> 4;
    __shared__ __align__(16) float Bs[16][BSROW];   // [mm][k], 12.5 KB
    const float* __restrict__ Edb = Ed + (size_t)b * NN * MP;

    float acc[2][12] = {};
    for (int mc = 0; mc < MP; mc += 16) {
        __syncthreads();
        // stage Bs[mm][k] for k in [0,192): 192k x 4 quads = 768 float4 loads
        #pragma unroll
        for (int it = 0; it < 3; ++it) {
            int idx = t + it * 256;                  // [0,768)
            int k = idx >> 2, mq = idx & 3;
            float4 v = make_float4(0.f, 0.f, 0.f, 0.f);
            if (k < NN)
                v = *reinterpret_cast<const float4*>(Edb + (size_t)k * MP + mc + mq * 4);
            Bs[mq * 4 + 0][k] = v.x;                 // transposed scalar writes;
            Bs[mq * 4 + 1][k] = v.y;                 // BSROW=196 -> conflict-free
            Bs[mq * 4 + 2][k] = v.z;
            Bs[mq * 4 + 3][k] = v.w;
        }
        __syncthreads();
        #pragma unroll
        for (int mm = 0; mm < 16; ++mm) {
            float2 av = *reinterpret_cast<const float2*>(&Bs[mm][r0 + ty * 2]);
            float a[2] = {av.x, av.y};
            float bb[12];
            #pragma unroll
            for (int off = 0; off < 3; ++off) {
                float4 bv = *reinterpret_cast<const float4*>(&Bs[mm][tx * 4 + off * 64]);
                bb[off * 4 + 0] = bv.x; bb[off * 4 + 1] = bv.y;
                bb[off * 4 + 2] = bv.z; bb[off * 4 + 3] = bv.w;
            }
            #pragma unroll
            for (int ii = 0; ii < 2; ++ii)
                #pragma unroll
                for (int jj = 0; jj < 12; ++jj)
                    acc[ii][jj] = fmaf(a[ii], bb[jj], acc[ii][jj]);
        }
    }

    // In-register softmax. Thread's cols: k = tx*4 + jj + off*64 (12 cols).
    const float scale = 0.08838834764831845f;        // 1/sqrt(128)
    #pragma unroll
    for (int ii = 0; ii < 2; ++ii) {
        int n = r0 + ty * 2 + ii;
        float vv[12];
        float mx = -1.f;                             // valid scores are >= 0
        #pragma unroll
        for (int jj = 0; jj < 12; ++jj) {
            int k = tx * 4 + (jj & 3) + (jj >> 2) * 64;
            bool valid = (k < NN);
            float v = fmaxf(acc[ii][jj] * scale, 0.f);
            vv[jj] = valid ? v : -1.f;
            mx = fmaxf(mx, vv[jj]);
        }
        #pragma unroll
        for (int off = 8; off; off >>= 1) mx = fmaxf(mx, __shfl_xor(mx, off, 64));
        float ex[12], sum = 0.f;
        #pragma unroll
        for (int jj = 0; jj < 12; ++jj) {
            int k = tx * 4 + (jj & 3) + (jj >> 2) * 64;
            float e = (k < NN) ? __expf(vv[jj] - mx) : 0.f;
            ex[jj] = e;
            sum += e;
        }
        #pragma unroll
        for (int off = 8; off; off >>= 1) sum += __shfl_xor(sum, off, 64);
        float inv = 1.f / sum;
        if (n < NN) {
            float* Pr = P + ((size_t)(b * NN + n)) * MP;
            #pragma unroll
            for (int off = 0; off < 3; ++off) {
                int k = tx * 4 + off * 64;
                if (k >= MP) continue;               // off==2 && tx>=12
                float4 v;                            // cols >=170 are pad: e==0
                v.x = ex[off * 4 + 0] * inv; v.y = ex[off * 4 + 1] * inv;
                v.z = ex[off * 4 + 2] * inv; v.w = ex[off * 4 + 3] * inv;
                *reinterpret_cast<float4*>(Pr + k) = v;
            }
        }
    }
}

// ---------------------------------------------------------------------------
// K4a: batch-partial means -- grid (113, 8); block y sums 16 batches.
// K4b: combine 8 partials + threshold.
// ---------------------------------------------------------------------------
__global__ __launch_bounds__(256) void k4a_partial(const float* __restrict__ P,
                                                   float* __restrict__ Pm) {
    int p = blockIdx.x * 256 + threadIdx.x;
    if (p >= NN * NN) return;
    int n = p / NN, k = p - n * NN;
    const float* base = P + (size_t)blockIdx.y * 16 * NN * MP + (size_t)n * MP + k;
    float s = 0.f;
    #pragma unroll
    for (int b = 0; b < 16; ++b) s += base[(size_t)b * NN * MP];
    Pm[blockIdx.y * (NN * NN) + p] = s;
}

__global__ __launch_bounds__(256) void k4b_thresh(const float* __restrict__ Pm,
                                                  float* __restrict__ out) {
    int p = blockIdx.x * 256 + threadIdx.x;
    if (p >= NN * NN) return;
    float s = 0.f;
    #pragma unroll
    for (int g = 0; g < 8; ++g) s += Pm[g * (NN * NN) + p];
    out[p] = (s * (1.f / 128.f) > 0.5f) ? 1.f : 0.f;
}

// ---------------------------------------------------------------------------
// Workspace layout (floats):
//   [0, P_SZ)            : P (padded 176)  -- first aliased as xs (XS_SZ) and
//                          Esp (at XS_SZ), both dead once K2 finishes.
//   [P_SZ, P_SZ+ED_SZ)   : Ed (padded 176) -- reused as Pm by K4a (Ed dead).
// Total = (3,829,760 + 3,829,760) * 4 B = 30.64 MB.
// ---------------------------------------------------------------------------
extern "C" void kernel_launch(void* const* d_in, const int* in_sizes, int n_in,
                              void* d_out, int out_size, void* d_ws, size_t ws_size,
                              hipStream_t stream) {
    const float* x  = (const float*)d_in[0];   // [128,128,170,12] f32
    const float* Es = (const float*)d_in[1];   // [128,170] f32
    float* out = (float*)d_out;                // [170,170] f32
    float* wsf = (float*)d_ws;

    float* P   = wsf;
    float* xs  = wsf;                 // aliases P region
    float* Esp = wsf + XS_SZ;         // aliases P region (tail)
    float* Ed  = wsf + P_SZ;
    float* Pm  = Ed;                  // reuses Ed region after K3

    k1_reduce_pad<<<10968, 256, 0, stream>>>(x, Es, xs, Esp);
    k2_embed<<<dim3(6, 128), 256, 0, stream>>>(xs, Esp, Ed);
    k3_scores<<<dim3(6, 128), 256, 0, stream>>>(Ed, P);
    k4a_partial<<<dim3(113, 8), 256, 0, stream>>>(P, Pm);
    k4b_thresh<<<113, 256, 0, stream>>>(Pm, out);
}